// Round 10
// baseline (314.513 us; speedup 1.0000x reference)
//
#include <hip/hip_runtime.h>
#include <hip/hip_fp16.h>

#define NEG_SLOPE 0.2f
#define BKT_SHIFT 8
#define BKT_NODES 256
#define BKT_CAP 10240
#define SRC_SHIFT 18
#define SRC_MASK 0x3FFFF
#define CHUNK 8192
#define NBMAX 512

typedef _Float16 half8 __attribute__((ext_vector_type(8)));
typedef float float4v __attribute__((ext_vector_type(4)));

__device__ __forceinline__ int wave_iscan(int v, int lane) {
#pragma unroll
    for (int off = 1; off < 64; off <<= 1) {
        int u = __shfl_up(v, off);
        if (lane >= off) v += u;
    }
    return v;
}

// ---------------- Fat kernel: bucketA (blocks < NBKT) || node1 (rest) ----------------
__global__ __launch_bounds__(512) void k_fat(
        const float* __restrict__ x, const int* __restrict__ type_ids,
        const float* __restrict__ type_emb, const float* __restrict__ W1,
        const float* __restrict__ a_src1, const float* __restrict__ a_dst1,
        __half2* __restrict__ h1h, float* __restrict__ als1, float* __restrict__ ald1,
        const int* __restrict__ ei, unsigned int* __restrict__ pk,
        int* __restrict__ bcnt, int E, int NBKT, int N)
{
    __shared__ unsigned int stage[CHUNK];
    __shared__ unsigned short stageB[CHUNK];
    __shared__ int cnt[NBMAX];
    __shared__ int excl[NBMAX];
    __shared__ int curp[NBMAX];
    __shared__ int gbase[NBMAX];
    __shared__ int wpart[8];

    int t = threadIdx.x;
    if (blockIdx.x < (unsigned)NBKT) {
        // ---------------- bucketA body (verbatim R8) ----------------
        int lane = t & 63, wv = t >> 6;
        int e0 = blockIdx.x * CHUNK;
        bool vec4 = ((E & 3) == 0);

        cnt[t] = 0;
        __syncthreads();

        int4 s4[4], d4[4];
        bool val[4];

        if (vec4) {
#pragma unroll
            for (int it = 0; it < 4; it++) {
                int e = e0 + it * 2048 + t * 4;
                val[it] = (e < E);
                if (val[it]) {
                    s4[it] = *(const int4*)(ei + e);
                    d4[it] = *(const int4*)(ei + (size_t)E + e);
                    atomicAdd(&cnt[d4[it].x >> BKT_SHIFT], 1);
                    atomicAdd(&cnt[d4[it].y >> BKT_SHIFT], 1);
                    atomicAdd(&cnt[d4[it].z >> BKT_SHIFT], 1);
                    atomicAdd(&cnt[d4[it].w >> BKT_SHIFT], 1);
                }
            }
        } else {
            for (int i = t; i < CHUNK; i += 512) {
                int e = e0 + i;
                if (e >= E) break;
                atomicAdd(&cnt[ei[E + e] >> BKT_SHIFT], 1);
            }
        }
        __syncthreads();
        int myc = cnt[t];
        int incl = wave_iscan(myc, lane);
        if (lane == 63) wpart[wv] = incl;
        __syncthreads();
#pragma unroll
        for (int k = 0; k < 8; k++)
            if (k < wv) incl += wpart[k];
        {
            int ex = incl - myc;
            excl[t] = ex;
            curp[t] = ex;
            if (t < NBKT)
                gbase[t] = (myc > 0) ? atomicAdd(&bcnt[t], myc) : 0;
        }
        __syncthreads();
        if (vec4) {
#pragma unroll
            for (int it = 0; it < 4; it++) {
                if (!val[it]) continue;
                int ss[4] = {s4[it].x, s4[it].y, s4[it].z, s4[it].w};
                int dd[4] = {d4[it].x, d4[it].y, d4[it].z, d4[it].w};
#pragma unroll
                for (int k = 0; k < 4; k++) {
                    int b = dd[k] >> BKT_SHIFT;
                    int p = atomicAdd(&curp[b], 1);
                    stage[p] = (unsigned)ss[k] | ((unsigned)(dd[k] & (BKT_NODES - 1)) << SRC_SHIFT);
                    stageB[p] = (unsigned short)b;
                }
            }
        } else {
            for (int i = t; i < CHUNK; i += 512) {
                int e = e0 + i;
                if (e >= E) break;
                int s = ei[e], d = ei[E + e];
                int b = d >> BKT_SHIFT;
                int p = atomicAdd(&curp[b], 1);
                stage[p] = (unsigned)s | ((unsigned)(d & (BKT_NODES - 1)) << SRC_SHIFT);
                stageB[p] = (unsigned short)b;
            }
        }
        __syncthreads();
        int total = E - e0; if (total > CHUNK) total = CHUNK;
        for (int i = t; i < total; i += 512) {
            int b = stageB[i];
            int idx = gbase[b] + (i - excl[b]);
            if (idx < BKT_CAP) pk[(size_t)b * BKT_CAP + idx] = stage[i];
        }
    } else {
        // ---------------- node1 body (8 nodes/block) ----------------
        int node = (blockIdx.x - NBKT) * 8 + (t >> 6);
        int j = t & 63;
        if (node >= N) return;

        float xin[21];
#pragma unroll
        for (int k = 0; k < 5; k++) xin[k] = x[node * 5 + k];
        int ty = type_ids[node];
#pragma unroll
        for (int k = 0; k < 16; k++) xin[5 + k] = type_emb[ty * 16 + k];

        float h = 0.f;
#pragma unroll
        for (int k = 0; k < 21; k++) h += xin[k] * W1[k * 64 + j];

        float hn = __shfl_xor(h, 1);
        if ((j & 1) == 0)
            h1h[node * 32 + (j >> 1)] = __floats2half2_rn(h, hn);

        int head = j >> 5, lane = j & 31;
        float ps = h * a_src1[head * 32 + lane];
        float pd = h * a_dst1[head * 32 + lane];
#pragma unroll
        for (int m = 16; m >= 1; m >>= 1) { ps += __shfl_xor(ps, m); pd += __shfl_xor(pd, m); }
        if (lane == 0) { als1[node * 2 + head] = ps; ald1[node * 2 + head] = pd; }
    }
}

// ---------------- Fused: per-bucket sort + gather layer 1 + MFMA projection ----------------
__global__ __launch_bounds__(512) void k_gbsm1(
        const unsigned int* __restrict__ pk, const int* __restrict__ bcnt,
        const float4* __restrict__ h4, const float* __restrict__ als1,
        const float* __restrict__ ald1, const float* __restrict__ b1,
        const float* __restrict__ W2, const float* __restrict__ a_src2,
        const float* __restrict__ a_dst2,
        int* __restrict__ rs, int* __restrict__ cur, int* __restrict__ ssrc,
        _Float16* __restrict__ h3h, float* __restrict__ als2,
        float* __restrict__ ald2, int N)
{
    __shared__ int cnt[BKT_NODES];
    __shared__ int cursor[BKT_NODES];
    __shared__ int nodebeg[BKT_NODES];
    __shared__ int red[512];
    __shared__ int wpart[4];
    __shared__ _Float16 h2t[BKT_NODES][72];
    __shared__ _Float16 w2t[64][72];

    int b = blockIdx.x;
    int t = threadIdx.x;
    int lane = t & 63, wv = t >> 6;
    int nb = min(bcnt[b], BKT_CAP);
    int nbase = b << BKT_SHIFT;
    int nn = min(BKT_NODES, N - nbase);

    // stage W2 (completes before the pre-MFMA barrier)
    for (int e = t; e < 4096; e += 512) {
        int kk = e >> 6, nc = e & 63;
        w2t[nc][kk] = (_Float16)W2[e];
    }

    // ---- sort phase (R9 verbatim) ----
    int part = 0;
    for (int i2 = t; i2 < b; i2 += 512) part += min(bcnt[i2], BKT_CAP);
    red[t] = part;
    if (t < BKT_NODES) cnt[t] = 0;
    __syncthreads();
    for (int off = 256; off; off >>= 1) {
        if (t < off) red[t] += red[t + off];
        __syncthreads();
    }
    int bs = red[0];

    const unsigned int* mypk = pk + (size_t)b * BKT_CAP;
    int nb4 = nb & ~3;
    for (int e = t * 4; e < nb4; e += 2048) {
        uint4 v = *(const uint4*)(mypk + e);
        atomicAdd(&cnt[v.x >> SRC_SHIFT], 1);
        atomicAdd(&cnt[v.y >> SRC_SHIFT], 1);
        atomicAdd(&cnt[v.z >> SRC_SHIFT], 1);
        atomicAdd(&cnt[v.w >> SRC_SHIFT], 1);
    }
    for (int e = nb4 + t; e < nb; e += 512) {
        atomicAdd(&cnt[mypk[e] >> SRC_SHIFT], 1);
    }
    __syncthreads();
    if (t < BKT_NODES) {
        int myc = cnt[t];
        int incl = wave_iscan(myc, lane);
        if (lane == 63) wpart[wv] = incl;
        __syncthreads();
#pragma unroll
        for (int k = 0; k < 4; k++)
            if (k < wv) incl += wpart[k];
        int ex = incl - myc;
        cursor[t] = ex;
        nodebeg[t] = bs + ex;
        int node = nbase + t;
        if (node < N) { rs[node] = bs + ex; cur[node] = bs + ex + myc; }
    } else {
        __syncthreads();
    }
    __syncthreads();
    for (int e = t; e < nb; e += 512) {
        unsigned int w = mypk[e];
        int p = atomicAdd(&cursor[w >> SRC_SHIFT], 1);
        ssrc[bs + p] = (int)(w & SRC_MASK);
    }
    __syncthreads();   // drains vmcnt: ssrc stores visible via local L2

    // ---- walk phase (R9 verbatim; h2 -> LDS) ----
    int l = t & 63;
    int q = l & 15, i = q & 7, hlf = q >> 3;
    int grpbase = l & 48;
    int head = i >> 2;
    int g = t >> 4;

    for (int ln = g; ln < BKT_NODES; ln += 32) {
        bool live = ln < nn;
        int lnc = live ? ln : (nn - 1);
        int node = nbase + lnc;
        int beg = nodebeg[lnc];
        int cnt_n = live ? cnt[lnc] : 0;

        float ad0 = ald1[node * 2 + 0];
        float ad1 = ald1[node * 2 + 1];
        float ad = head ? ad1 : ad0;

        int mc = cnt_n;
        mc = max(mc, __shfl_xor(mc, 16));
        mc = max(mc, __shfl_xor(mc, 32));

        float acc[8];
#pragma unroll
        for (int k = 0; k < 8; k++) acc[k] = 0.f;
        float wsum = 0.f;

        for (int bb = 0; bb < mc; bb += 16) {
            int slot = bb + q;
            bool valid = slot < cnt_n;
            int idx = valid ? (beg + slot) : 0;
            int s = ssrc[idx];
            if (!valid) s = node;
            float2 al = *(const float2*)(als1 + (size_t)s * 2);
            float lg0 = al.x + ad0; lg0 = (lg0 >= 0.f) ? lg0 : NEG_SLOPE * lg0;
            float lg1 = al.y + ad1; lg1 = (lg1 >= 0.f) ? lg1 : NEG_SLOPE * lg1;
            float w0 = valid ? __expf(lg0) : 0.f;
            float w1 = valid ? __expf(lg1) : 0.f;
            __half2 wp = __floats2half2_rn(w0, w1);
            unsigned wpi = *(unsigned*)&wp;

#pragma unroll
            for (int r = 0; r < 8; r++) {
                int srcl = grpbase + hlf * 8 + r;
                int sr = __shfl(s, srcl);
                unsigned wri = __shfl(wpi, srcl);
                __half2 wh = *(__half2*)&wri;
                float w = head ? __high2float(wh) : __low2float(wh);
                float4 rv = h4[(size_t)sr * 8 + i];
                const __half* hp = (const __half*)&rv;
#pragma unroll
                for (int k = 0; k < 8; k++)
                    acc[k] = fmaf(w, __half2float(hp[k]), acc[k]);
                wsum += w;
            }
        }

#pragma unroll
        for (int k = 0; k < 8; k++) acc[k] += __shfl_xor(acc[k], 8);
        wsum += __shfl_xor(wsum, 8);

        // self loop
        {
            float lg = als1[node * 2 + head] + ad;
            lg = (lg >= 0.f) ? lg : NEG_SLOPE * lg;
            float w = __expf(lg);
            float4 rv = h4[(size_t)node * 8 + i];
            const __half* hp = (const __half*)&rv;
#pragma unroll
            for (int k = 0; k < 8; k++)
                acc[k] = fmaf(w, __half2float(hp[k]), acc[k]);
            wsum += w;
        }

        float inv = 1.f / (wsum + 1e-16f);
        if (hlf == 0) {
            union { float4 f4; __half2 h2[4]; } u;
#pragma unroll
            for (int c4 = 0; c4 < 4; c4++) {
                float v0 = fmaxf(acc[2*c4]   * inv + b1[i * 8 + 2*c4],     0.f);
                float v1 = fmaxf(acc[2*c4+1] * inv + b1[i * 8 + 2*c4 + 1], 0.f);
                u.h2[c4] = __floats2half2_rn(v0, v1);
            }
            *(float4*)(&h2t[ln][i * 8]) = u.f4;
        }
    }
    __syncthreads();

    // ---- MFMA phase: h3 = h2t @ W2, logits, stores ----
    int l15 = lane & 15, quad = lane >> 4;
#pragma unroll
    for (int rti = 0; rti < 2; rti++) {
        int rt = wv * 2 + rti;
        half8 a0 = *(const half8*)(&h2t[rt * 16 + l15][quad * 8]);
        half8 a1 = *(const half8*)(&h2t[rt * 16 + l15][32 + quad * 8]);
        float4v accs[4];
#pragma unroll
        for (int ct = 0; ct < 4; ct++) {
            half8 bf0 = *(const half8*)(&w2t[ct * 16 + l15][quad * 8]);
            half8 bf1 = *(const half8*)(&w2t[ct * 16 + l15][32 + quad * 8]);
            float4v c = {0.f, 0.f, 0.f, 0.f};
            c = __builtin_amdgcn_mfma_f32_16x16x32_f16(a0, bf0, c, 0, 0, 0);
            c = __builtin_amdgcn_mfma_f32_16x16x32_f16(a1, bf1, c, 0, 0, 0);
            accs[ct] = c;
        }
        float ps[4] = {0.f, 0.f, 0.f, 0.f};
        float pd[4] = {0.f, 0.f, 0.f, 0.f};
#pragma unroll
        for (int ct = 0; ct < 4; ct++) {
            float as = a_src2[ct * 16 + l15];
            float av = a_dst2[ct * 16 + l15];
#pragma unroll
            for (int r = 0; r < 4; r++) {
                ps[r] += accs[ct][r] * as;
                pd[r] += accs[ct][r] * av;
            }
        }
#pragma unroll
        for (int m = 1; m <= 8; m <<= 1) {
#pragma unroll
            for (int r = 0; r < 4; r++) {
                ps[r] += __shfl_xor(ps[r], m);
                pd[r] += __shfl_xor(pd[r], m);
            }
        }
#pragma unroll
        for (int r = 0; r < 4; r++) {
            int row = rt * 16 + quad * 4 + r;
            int node = nbase + row;
            if (node < N) {
                if (l15 == 0) { als2[node] = ps[r]; ald2[node] = pd[r]; }
#pragma unroll
                for (int ct = 0; ct < 4; ct++)
                    h3h[(size_t)node * 64 + ct * 16 + l15] = (_Float16)accs[ct][r];
            }
        }
    }
}

// ---------------- Gather layer 2: 16 lanes/node, 4 nodes/wave + LayerNorm ----------------
__global__ void k_gather2(const int* __restrict__ rs, const int* __restrict__ cur,
                          const int* __restrict__ ssrc, const float4* __restrict__ h4,
                          const float* __restrict__ als2, const float* __restrict__ ald2,
                          const float* __restrict__ b2, const float* __restrict__ gamma,
                          const float* __restrict__ beta, float* __restrict__ out, int N)
{
    int t = threadIdx.x;
    int l = t & 63;
    int q = l & 15;
    int i = q & 7;
    int hlf = q >> 3;
    int grpbase = l & 48;

    int node = blockIdx.x * 16 + (t >> 4);
    bool live = node < N;
    int node_c = live ? node : (N - 1);

    int beg = rs[node_c];
    int cnt = live ? (cur[node_c] - beg) : 0;
    float ad = ald2[node_c];

    int mc = cnt;
    mc = max(mc, __shfl_xor(mc, 16));
    mc = max(mc, __shfl_xor(mc, 32));

    float acc[8];
#pragma unroll
    for (int k = 0; k < 8; k++) acc[k] = 0.f;
    float wsum = 0.f;

    for (int b = 0; b < mc; b += 16) {
        int slot = b + q;
        bool valid = slot < cnt;
        int idx = valid ? (beg + slot) : 0;
        int s = ssrc[idx];
        if (!valid) s = node_c;
        float lg = als2[s] + ad;
        lg = (lg >= 0.f) ? lg : NEG_SLOPE * lg;
        float w = valid ? __expf(lg) : 0.f;

#pragma unroll
        for (int r = 0; r < 8; r++) {
            int srcl = grpbase + hlf * 8 + r;
            int sr = __shfl(s, srcl);
            float wr = __shfl(w, srcl);
            float4 rv = h4[(size_t)sr * 8 + i];
            const __half* hp = (const __half*)&rv;
#pragma unroll
            for (int k = 0; k < 8; k++)
                acc[k] = fmaf(wr, __half2float(hp[k]), acc[k]);
            wsum += wr;
        }
    }

#pragma unroll
    for (int k = 0; k < 8; k++) acc[k] += __shfl_xor(acc[k], 8);
    wsum += __shfl_xor(wsum, 8);

    // self loop
    {
        float lg = als2[node_c] + ad;
        lg = (lg >= 0.f) ? lg : NEG_SLOPE * lg;
        float w = __expf(lg);
        float4 rv = h4[(size_t)node_c * 8 + i];
        const __half* hp = (const __half*)&rv;
#pragma unroll
        for (int k = 0; k < 8; k++)
            acc[k] = fmaf(w, __half2float(hp[k]), acc[k]);
        wsum += w;
    }

    float inv = 1.f / (wsum + 1e-16f);
    float o[8];
    float s = 0.f;
#pragma unroll
    for (int k = 0; k < 8; k++) { o[k] = acc[k] * inv + b2[i * 8 + k]; s += o[k]; }
    s += __shfl_xor(s, 1); s += __shfl_xor(s, 2); s += __shfl_xor(s, 4);
    float mu = s * (1.f / 64.f);
    float v = 0.f;
#pragma unroll
    for (int k = 0; k < 8; k++) { float d = o[k] - mu; v += d * d; }
    v += __shfl_xor(v, 1); v += __shfl_xor(v, 2); v += __shfl_xor(v, 4);
    v *= (1.f / 64.f);
    float rstd = rsqrtf(v + 1e-5f);
    if (live && hlf == 0) {
        float res[8];
#pragma unroll
        for (int k = 0; k < 8; k++)
            res[k] = (o[k] - mu) * rstd * gamma[i * 8 + k] + beta[i * 8 + k];
        float4* op = (float4*)(out + (size_t)node * 64 + i * 8);
        op[0] = make_float4(res[0], res[1], res[2], res[3]);
        op[1] = make_float4(res[4], res[5], res[6], res[7]);
    }
}

extern "C" void kernel_launch(void* const* d_in, const int* in_sizes, int n_in,
                              void* d_out, int out_size, void* d_ws, size_t ws_size,
                              hipStream_t stream) {
    const float* x        = (const float*)d_in[0];
    const int*   ei       = (const int*)  d_in[1];
    const int*   type_ids = (const int*)  d_in[2];
    const float* type_emb = (const float*)d_in[3];
    const float* W1       = (const float*)d_in[4];
    const float* a_src1   = (const float*)d_in[5];
    const float* a_dst1   = (const float*)d_in[6];
    const float* b1       = (const float*)d_in[7];
    const float* W2       = (const float*)d_in[8];
    const float* a_src2   = (const float*)d_in[9];
    const float* a_dst2   = (const float*)d_in[10];
    const float* b2       = (const float*)d_in[11];
    const float* gamma    = (const float*)d_in[12];
    const float* beta     = (const float*)d_in[13];

    int N = in_sizes[0] / 5;
    int E = in_sizes[1] / 2;
    int NBKT = (N + BKT_NODES - 1) >> BKT_SHIFT;

    char* base = (char*)d_ws;
    size_t off = 0;
    auto carve = [&](size_t bytes) { void* p = base + off; off += (bytes + 255) & ~(size_t)255; return p; };
    __half2* h1h = (__half2*)carve((size_t)N * 64 * sizeof(__half));
    unsigned int* pk = (unsigned int*)carve((size_t)NBKT * BKT_CAP * sizeof(unsigned int));
    _Float16* h3h = (_Float16*)carve((size_t)N * 64 * sizeof(__half));
    float* als1  = (float*)carve((size_t)N * 2 * sizeof(float));
    float* ald1  = (float*)carve((size_t)N * 2 * sizeof(float));
    float* als2  = (float*)carve((size_t)N * sizeof(float));
    float* ald2  = (float*)carve((size_t)N * sizeof(float));
    int*   rs    = (int*)carve((size_t)N * sizeof(int));
    int*   cur   = (int*)carve((size_t)N * sizeof(int));
    int*   bcnt  = (int*)carve(1024 * sizeof(int));
    int*   ssrc  = (int*)carve((size_t)E * sizeof(int) + 256);

    dim3 tb(256);
    dim3 tb512(512);

    hipMemsetAsync(bcnt, 0, NBKT * sizeof(int), stream);

    int nodeblks = (N + 7) / 8;
    k_fat<<<dim3(NBKT + nodeblks), tb512, 0, stream>>>(
        x, type_ids, type_emb, W1, a_src1, a_dst1, h1h, als1, ald1,
        ei, pk, bcnt, E, NBKT, N);

    k_gbsm1<<<dim3(NBKT), tb512, 0, stream>>>(
        pk, bcnt, (const float4*)h1h, als1, ald1, b1,
        W2, a_src2, a_dst2, rs, cur, ssrc, h3h, als2, ald2, N);

    dim3 ng((N + 15) / 16);
    k_gather2<<<ng, tb, 0, stream>>>(rs, cur, ssrc, (const float4*)h3h, als2, ald2, b2,
                                     gamma, beta, (float*)d_out, N);
}

// Round 11
// 299.775 us; speedup vs baseline: 1.0492x; 1.0492x over previous
//
#include <hip/hip_runtime.h>
#include <hip/hip_fp16.h>

#define NEG_SLOPE 0.2f
#define BKT_SHIFT 8
#define BKT_NODES 256
#define BKT_CAP 10240
#define SRC_SHIFT 18
#define SRC_MASK 0x3FFFF
#define CHUNK 8192
#define NBMAX 512

typedef _Float16 half8 __attribute__((ext_vector_type(8)));
typedef float float4v __attribute__((ext_vector_type(4)));

__device__ __forceinline__ int wave_iscan(int v, int lane) {
#pragma unroll
    for (int off = 1; off < 64; off <<= 1) {
        int u = __shfl_up(v, off);
        if (lane >= off) v += u;
    }
    return v;
}

// ---------------- Fused: node1 pre-phase + bucketA (same blocks, shared LDS budget) ----------------
__global__ __launch_bounds__(512) void k_bkn1(
        const float* __restrict__ x, const int* __restrict__ type_ids,
        const float* __restrict__ type_emb, const float* __restrict__ W1,
        const float* __restrict__ a_src1, const float* __restrict__ a_dst1,
        __half2* __restrict__ h1h, float* __restrict__ als1, float* __restrict__ ald1,
        const int* __restrict__ ei, unsigned int* __restrict__ pk,
        int* __restrict__ bcnt, int E, int NCHUNKS, int NBKT, int N)
{
    __shared__ unsigned int stage[CHUNK];
    __shared__ unsigned short stageB[CHUNK];
    __shared__ int cnt[NBMAX];
    __shared__ int excl[NBMAX];
    __shared__ int curp[NBMAX];
    __shared__ int gbase[NBMAX];
    __shared__ int wpart[8];

    int t = threadIdx.x;
    int lane = t & 63, wv = t >> 6;

    // ---- node1 pre-phase: this block's 256 nodes (no LDS used) ----
    {
        int nend = min((int)(blockIdx.x + 1) * 256, N);
        for (int node = blockIdx.x * 256 + wv; node < nend; node += 8) {
            int j = lane;
            float xin[21];
#pragma unroll
            for (int k = 0; k < 5; k++) xin[k] = x[node * 5 + k];
            int ty = type_ids[node];
#pragma unroll
            for (int k = 0; k < 16; k++) xin[5 + k] = type_emb[ty * 16 + k];

            float h = 0.f;
#pragma unroll
            for (int k = 0; k < 21; k++) h += xin[k] * W1[k * 64 + j];

            float hn = __shfl_xor(h, 1);
            if ((j & 1) == 0)
                h1h[node * 32 + (j >> 1)] = __floats2half2_rn(h, hn);

            int head = j >> 5, l31 = j & 31;
            float ps = h * a_src1[head * 32 + l31];
            float pd = h * a_dst1[head * 32 + l31];
#pragma unroll
            for (int m = 16; m >= 1; m >>= 1) { ps += __shfl_xor(ps, m); pd += __shfl_xor(pd, m); }
            if (l31 == 0) { als1[node * 2 + head] = ps; ald1[node * 2 + head] = pd; }
        }
    }

    // ---- bucketA phase (R8 verbatim) ----
    if (blockIdx.x >= (unsigned)NCHUNKS) return;

    int e0 = blockIdx.x * CHUNK;
    bool vec4 = ((E & 3) == 0);

    cnt[t] = 0;
    __syncthreads();

    int4 s4[4], d4[4];
    bool val[4];

    if (vec4) {
#pragma unroll
        for (int it = 0; it < 4; it++) {
            int e = e0 + it * 2048 + t * 4;
            val[it] = (e < E);
            if (val[it]) {
                s4[it] = *(const int4*)(ei + e);
                d4[it] = *(const int4*)(ei + (size_t)E + e);
                atomicAdd(&cnt[d4[it].x >> BKT_SHIFT], 1);
                atomicAdd(&cnt[d4[it].y >> BKT_SHIFT], 1);
                atomicAdd(&cnt[d4[it].z >> BKT_SHIFT], 1);
                atomicAdd(&cnt[d4[it].w >> BKT_SHIFT], 1);
            }
        }
    } else {
        for (int i = t; i < CHUNK; i += 512) {
            int e = e0 + i;
            if (e >= E) break;
            atomicAdd(&cnt[ei[E + e] >> BKT_SHIFT], 1);
        }
    }
    __syncthreads();
    int myc = cnt[t];
    int incl = wave_iscan(myc, lane);
    if (lane == 63) wpart[wv] = incl;
    __syncthreads();
#pragma unroll
    for (int k = 0; k < 8; k++)
        if (k < wv) incl += wpart[k];
    {
        int ex = incl - myc;
        excl[t] = ex;
        curp[t] = ex;
        if (t < NBKT)
            gbase[t] = (myc > 0) ? atomicAdd(&bcnt[t], myc) : 0;
    }
    __syncthreads();
    if (vec4) {
#pragma unroll
        for (int it = 0; it < 4; it++) {
            if (!val[it]) continue;
            int ss[4] = {s4[it].x, s4[it].y, s4[it].z, s4[it].w};
            int dd[4] = {d4[it].x, d4[it].y, d4[it].z, d4[it].w};
#pragma unroll
            for (int k = 0; k < 4; k++) {
                int b = dd[k] >> BKT_SHIFT;
                int p = atomicAdd(&curp[b], 1);
                stage[p] = (unsigned)ss[k] | ((unsigned)(dd[k] & (BKT_NODES - 1)) << SRC_SHIFT);
                stageB[p] = (unsigned short)b;
            }
        }
    } else {
        for (int i = t; i < CHUNK; i += 512) {
            int e = e0 + i;
            if (e >= E) break;
            int s = ei[e], d = ei[E + e];
            int b = d >> BKT_SHIFT;
            int p = atomicAdd(&curp[b], 1);
            stage[p] = (unsigned)s | ((unsigned)(d & (BKT_NODES - 1)) << SRC_SHIFT);
            stageB[p] = (unsigned short)b;
        }
    }
    __syncthreads();
    int total = E - e0; if (total > CHUNK) total = CHUNK;
    for (int i = t; i < total; i += 512) {
        int b = stageB[i];
        int idx = gbase[b] + (i - excl[b]);
        if (idx < BKT_CAP) pk[(size_t)b * BKT_CAP + idx] = stage[i];
    }
}

// ---------------- Fused: per-bucket sort + gather layer 1 + MFMA projection (R10 verbatim) ----------------
__global__ __launch_bounds__(512) void k_gbsm1(
        const unsigned int* __restrict__ pk, const int* __restrict__ bcnt,
        const float4* __restrict__ h4, const float* __restrict__ als1,
        const float* __restrict__ ald1, const float* __restrict__ b1,
        const float* __restrict__ W2, const float* __restrict__ a_src2,
        const float* __restrict__ a_dst2,
        int* __restrict__ rs, int* __restrict__ cur, int* __restrict__ ssrc,
        _Float16* __restrict__ h3h, float* __restrict__ als2,
        float* __restrict__ ald2, int N)
{
    __shared__ int cnt[BKT_NODES];
    __shared__ int cursor[BKT_NODES];
    __shared__ int nodebeg[BKT_NODES];
    __shared__ int red[512];
    __shared__ int wpart[4];
    __shared__ _Float16 h2t[BKT_NODES][72];
    __shared__ _Float16 w2t[64][72];

    int b = blockIdx.x;
    int t = threadIdx.x;
    int lane = t & 63, wv = t >> 6;
    int nb = min(bcnt[b], BKT_CAP);
    int nbase = b << BKT_SHIFT;
    int nn = min(BKT_NODES, N - nbase);

    for (int e = t; e < 4096; e += 512) {
        int kk = e >> 6, nc = e & 63;
        w2t[nc][kk] = (_Float16)W2[e];
    }

    // ---- sort phase ----
    int part = 0;
    for (int i2 = t; i2 < b; i2 += 512) part += min(bcnt[i2], BKT_CAP);
    red[t] = part;
    if (t < BKT_NODES) cnt[t] = 0;
    __syncthreads();
    for (int off = 256; off; off >>= 1) {
        if (t < off) red[t] += red[t + off];
        __syncthreads();
    }
    int bs = red[0];

    const unsigned int* mypk = pk + (size_t)b * BKT_CAP;
    int nb4 = nb & ~3;
    for (int e = t * 4; e < nb4; e += 2048) {
        uint4 v = *(const uint4*)(mypk + e);
        atomicAdd(&cnt[v.x >> SRC_SHIFT], 1);
        atomicAdd(&cnt[v.y >> SRC_SHIFT], 1);
        atomicAdd(&cnt[v.z >> SRC_SHIFT], 1);
        atomicAdd(&cnt[v.w >> SRC_SHIFT], 1);
    }
    for (int e = nb4 + t; e < nb; e += 512) {
        atomicAdd(&cnt[mypk[e] >> SRC_SHIFT], 1);
    }
    __syncthreads();
    if (t < BKT_NODES) {
        int myc = cnt[t];
        int incl = wave_iscan(myc, lane);
        if (lane == 63) wpart[wv] = incl;
        __syncthreads();
#pragma unroll
        for (int k = 0; k < 4; k++)
            if (k < wv) incl += wpart[k];
        int ex = incl - myc;
        cursor[t] = ex;
        nodebeg[t] = bs + ex;
        int node = nbase + t;
        if (node < N) { rs[node] = bs + ex; cur[node] = bs + ex + myc; }
    } else {
        __syncthreads();
    }
    __syncthreads();
    for (int e = t; e < nb; e += 512) {
        unsigned int w = mypk[e];
        int p = atomicAdd(&cursor[w >> SRC_SHIFT], 1);
        ssrc[bs + p] = (int)(w & SRC_MASK);
    }
    __syncthreads();

    // ---- walk phase ----
    int l = t & 63;
    int q = l & 15, i = q & 7, hlf = q >> 3;
    int grpbase = l & 48;
    int head = i >> 2;
    int g = t >> 4;

    for (int ln = g; ln < BKT_NODES; ln += 32) {
        bool live = ln < nn;
        int lnc = live ? ln : (nn - 1);
        int node = nbase + lnc;
        int beg = nodebeg[lnc];
        int cnt_n = live ? cnt[lnc] : 0;

        float ad0 = ald1[node * 2 + 0];
        float ad1 = ald1[node * 2 + 1];
        float ad = head ? ad1 : ad0;

        int mc = cnt_n;
        mc = max(mc, __shfl_xor(mc, 16));
        mc = max(mc, __shfl_xor(mc, 32));

        float acc[8];
#pragma unroll
        for (int k = 0; k < 8; k++) acc[k] = 0.f;
        float wsum = 0.f;

        for (int bb = 0; bb < mc; bb += 16) {
            int slot = bb + q;
            bool valid = slot < cnt_n;
            int idx = valid ? (beg + slot) : 0;
            int s = ssrc[idx];
            if (!valid) s = node;
            float2 al = *(const float2*)(als1 + (size_t)s * 2);
            float lg0 = al.x + ad0; lg0 = (lg0 >= 0.f) ? lg0 : NEG_SLOPE * lg0;
            float lg1 = al.y + ad1; lg1 = (lg1 >= 0.f) ? lg1 : NEG_SLOPE * lg1;
            float w0 = valid ? __expf(lg0) : 0.f;
            float w1 = valid ? __expf(lg1) : 0.f;
            __half2 wp = __floats2half2_rn(w0, w1);
            unsigned wpi = *(unsigned*)&wp;

#pragma unroll
            for (int r = 0; r < 8; r++) {
                int srcl = grpbase + hlf * 8 + r;
                int sr = __shfl(s, srcl);
                unsigned wri = __shfl(wpi, srcl);
                __half2 wh = *(__half2*)&wri;
                float w = head ? __high2float(wh) : __low2float(wh);
                float4 rv = h4[(size_t)sr * 8 + i];
                const __half* hp = (const __half*)&rv;
#pragma unroll
                for (int k = 0; k < 8; k++)
                    acc[k] = fmaf(w, __half2float(hp[k]), acc[k]);
                wsum += w;
            }
        }

#pragma unroll
        for (int k = 0; k < 8; k++) acc[k] += __shfl_xor(acc[k], 8);
        wsum += __shfl_xor(wsum, 8);

        // self loop
        {
            float lg = als1[node * 2 + head] + ad;
            lg = (lg >= 0.f) ? lg : NEG_SLOPE * lg;
            float w = __expf(lg);
            float4 rv = h4[(size_t)node * 8 + i];
            const __half* hp = (const __half*)&rv;
#pragma unroll
            for (int k = 0; k < 8; k++)
                acc[k] = fmaf(w, __half2float(hp[k]), acc[k]);
            wsum += w;
        }

        float inv = 1.f / (wsum + 1e-16f);
        if (hlf == 0) {
            union { float4 f4; __half2 h2[4]; } u;
#pragma unroll
            for (int c4 = 0; c4 < 4; c4++) {
                float v0 = fmaxf(acc[2*c4]   * inv + b1[i * 8 + 2*c4],     0.f);
                float v1 = fmaxf(acc[2*c4+1] * inv + b1[i * 8 + 2*c4 + 1], 0.f);
                u.h2[c4] = __floats2half2_rn(v0, v1);
            }
            *(float4*)(&h2t[ln][i * 8]) = u.f4;
        }
    }
    __syncthreads();

    // ---- MFMA phase ----
    int l15 = lane & 15, quad = lane >> 4;
#pragma unroll
    for (int rti = 0; rti < 2; rti++) {
        int rt = wv * 2 + rti;
        half8 a0 = *(const half8*)(&h2t[rt * 16 + l15][quad * 8]);
        half8 a1 = *(const half8*)(&h2t[rt * 16 + l15][32 + quad * 8]);
        float4v accs[4];
#pragma unroll
        for (int ct = 0; ct < 4; ct++) {
            half8 bf0 = *(const half8*)(&w2t[ct * 16 + l15][quad * 8]);
            half8 bf1 = *(const half8*)(&w2t[ct * 16 + l15][32 + quad * 8]);
            float4v c = {0.f, 0.f, 0.f, 0.f};
            c = __builtin_amdgcn_mfma_f32_16x16x32_f16(a0, bf0, c, 0, 0, 0);
            c = __builtin_amdgcn_mfma_f32_16x16x32_f16(a1, bf1, c, 0, 0, 0);
            accs[ct] = c;
        }
        float ps[4] = {0.f, 0.f, 0.f, 0.f};
        float pd[4] = {0.f, 0.f, 0.f, 0.f};
#pragma unroll
        for (int ct = 0; ct < 4; ct++) {
            float as = a_src2[ct * 16 + l15];
            float av = a_dst2[ct * 16 + l15];
#pragma unroll
            for (int r = 0; r < 4; r++) {
                ps[r] += accs[ct][r] * as;
                pd[r] += accs[ct][r] * av;
            }
        }
#pragma unroll
        for (int m = 1; m <= 8; m <<= 1) {
#pragma unroll
            for (int r = 0; r < 4; r++) {
                ps[r] += __shfl_xor(ps[r], m);
                pd[r] += __shfl_xor(pd[r], m);
            }
        }
#pragma unroll
        for (int r = 0; r < 4; r++) {
            int row = rt * 16 + quad * 4 + r;
            int node = nbase + row;
            if (node < N) {
                if (l15 == 0) { als2[node] = ps[r]; ald2[node] = pd[r]; }
#pragma unroll
                for (int ct = 0; ct < 4; ct++)
                    h3h[(size_t)node * 64 + ct * 16 + l15] = (_Float16)accs[ct][r];
            }
        }
    }
}

// ---------------- Gather layer 2: 16 lanes/node, 4 nodes/wave + LayerNorm ----------------
__global__ void k_gather2(const int* __restrict__ rs, const int* __restrict__ cur,
                          const int* __restrict__ ssrc, const float4* __restrict__ h4,
                          const float* __restrict__ als2, const float* __restrict__ ald2,
                          const float* __restrict__ b2, const float* __restrict__ gamma,
                          const float* __restrict__ beta, float* __restrict__ out, int N)
{
    int t = threadIdx.x;
    int l = t & 63;
    int q = l & 15;
    int i = q & 7;
    int hlf = q >> 3;
    int grpbase = l & 48;

    int node = blockIdx.x * 16 + (t >> 4);
    bool live = node < N;
    int node_c = live ? node : (N - 1);

    int beg = rs[node_c];
    int cnt = live ? (cur[node_c] - beg) : 0;
    float ad = ald2[node_c];

    int mc = cnt;
    mc = max(mc, __shfl_xor(mc, 16));
    mc = max(mc, __shfl_xor(mc, 32));

    float acc[8];
#pragma unroll
    for (int k = 0; k < 8; k++) acc[k] = 0.f;
    float wsum = 0.f;

    for (int b = 0; b < mc; b += 16) {
        int slot = b + q;
        bool valid = slot < cnt;
        int idx = valid ? (beg + slot) : 0;
        int s = ssrc[idx];
        if (!valid) s = node_c;
        float lg = als2[s] + ad;
        lg = (lg >= 0.f) ? lg : NEG_SLOPE * lg;
        float w = valid ? __expf(lg) : 0.f;

#pragma unroll
        for (int r = 0; r < 8; r++) {
            int srcl = grpbase + hlf * 8 + r;
            int sr = __shfl(s, srcl);
            float wr = __shfl(w, srcl);
            float4 rv = h4[(size_t)sr * 8 + i];
            const __half* hp = (const __half*)&rv;
#pragma unroll
            for (int k = 0; k < 8; k++)
                acc[k] = fmaf(wr, __half2float(hp[k]), acc[k]);
            wsum += wr;
        }
    }

#pragma unroll
    for (int k = 0; k < 8; k++) acc[k] += __shfl_xor(acc[k], 8);
    wsum += __shfl_xor(wsum, 8);

    // self loop
    {
        float lg = als2[node_c] + ad;
        lg = (lg >= 0.f) ? lg : NEG_SLOPE * lg;
        float w = __expf(lg);
        float4 rv = h4[(size_t)node_c * 8 + i];
        const __half* hp = (const __half*)&rv;
#pragma unroll
        for (int k = 0; k < 8; k++)
            acc[k] = fmaf(w, __half2float(hp[k]), acc[k]);
        wsum += w;
    }

    float inv = 1.f / (wsum + 1e-16f);
    float o[8];
    float s = 0.f;
#pragma unroll
    for (int k = 0; k < 8; k++) { o[k] = acc[k] * inv + b2[i * 8 + k]; s += o[k]; }
    s += __shfl_xor(s, 1); s += __shfl_xor(s, 2); s += __shfl_xor(s, 4);
    float mu = s * (1.f / 64.f);
    float v = 0.f;
#pragma unroll
    for (int k = 0; k < 8; k++) { float d = o[k] - mu; v += d * d; }
    v += __shfl_xor(v, 1); v += __shfl_xor(v, 2); v += __shfl_xor(v, 4);
    v *= (1.f / 64.f);
    float rstd = rsqrtf(v + 1e-5f);
    if (live && hlf == 0) {
        float res[8];
#pragma unroll
        for (int k = 0; k < 8; k++)
            res[k] = (o[k] - mu) * rstd * gamma[i * 8 + k] + beta[i * 8 + k];
        float4* op = (float4*)(out + (size_t)node * 64 + i * 8);
        op[0] = make_float4(res[0], res[1], res[2], res[3]);
        op[1] = make_float4(res[4], res[5], res[6], res[7]);
    }
}

extern "C" void kernel_launch(void* const* d_in, const int* in_sizes, int n_in,
                              void* d_out, int out_size, void* d_ws, size_t ws_size,
                              hipStream_t stream) {
    const float* x        = (const float*)d_in[0];
    const int*   ei       = (const int*)  d_in[1];
    const int*   type_ids = (const int*)  d_in[2];
    const float* type_emb = (const float*)d_in[3];
    const float* W1       = (const float*)d_in[4];
    const float* a_src1   = (const float*)d_in[5];
    const float* a_dst1   = (const float*)d_in[6];
    const float* b1       = (const float*)d_in[7];
    const float* W2       = (const float*)d_in[8];
    const float* a_src2   = (const float*)d_in[9];
    const float* a_dst2   = (const float*)d_in[10];
    const float* b2       = (const float*)d_in[11];
    const float* gamma    = (const float*)d_in[12];
    const float* beta     = (const float*)d_in[13];

    int N = in_sizes[0] / 5;
    int E = in_sizes[1] / 2;
    int NBKT = (N + BKT_NODES - 1) >> BKT_SHIFT;
    int NCHUNKS = (E + CHUNK - 1) / CHUNK;

    char* base = (char*)d_ws;
    size_t off = 0;
    auto carve = [&](size_t bytes) { void* p = base + off; off += (bytes + 255) & ~(size_t)255; return p; };
    __half2* h1h = (__half2*)carve((size_t)N * 64 * sizeof(__half));
    unsigned int* pk = (unsigned int*)carve((size_t)NBKT * BKT_CAP * sizeof(unsigned int));
    _Float16* h3h = (_Float16*)carve((size_t)N * 64 * sizeof(__half));
    float* als1  = (float*)carve((size_t)N * 2 * sizeof(float));
    float* ald1  = (float*)carve((size_t)N * 2 * sizeof(float));
    float* als2  = (float*)carve((size_t)N * sizeof(float));
    float* ald2  = (float*)carve((size_t)N * sizeof(float));
    int*   rs    = (int*)carve((size_t)N * sizeof(int));
    int*   cur   = (int*)carve((size_t)N * sizeof(int));
    int*   bcnt  = (int*)carve(1024 * sizeof(int));
    int*   ssrc  = (int*)carve((size_t)E * sizeof(int) + 256);

    dim3 tb(256);
    dim3 tb512(512);

    hipMemsetAsync(bcnt, 0, 1024 * sizeof(int), stream);

    int nodeblks = (N + 255) / 256;
    int fatgrid = NCHUNKS > nodeblks ? NCHUNKS : nodeblks;
    k_bkn1<<<dim3(fatgrid), tb512, 0, stream>>>(
        x, type_ids, type_emb, W1, a_src1, a_dst1, h1h, als1, ald1,
        ei, pk, bcnt, E, NCHUNKS, NBKT, N);

    k_gbsm1<<<dim3(NBKT), tb512, 0, stream>>>(
        pk, bcnt, (const float4*)h1h, als1, ald1, b1,
        W2, a_src2, a_dst2, rs, cur, ssrc, h3h, als2, ald2, N);

    dim3 ng((N + 15) / 16);
    k_gather2<<<ng, tb, 0, stream>>>(rs, cur, ssrc, (const float4*)h3h, als2, ald2, b2,
                                     gamma, beta, (float*)d_out, N);
}